// Round 4
// baseline (317.789 us; speedup 1.0000x reference)
//
#include <hip/hip_runtime.h>
#include <cstddef>

#define B_ 64
#define T_ 1000
#define F_ 512
#define H_ 8
#define KD_ 32
#define HK_ 256   // H_*KD_
#define NC_ 32    // t-chunks: 8 of 32 + 24 of 31 = 1000

// ---------------- K1: qh[h,k] = sum_f q[f]*Wq[f,h,k] + bq[h,k] ----------------
__global__ __launch_bounds__(64) void k_qh(const float* __restrict__ q,
                                           const float* __restrict__ Wq,
                                           const float* __restrict__ bq,
                                           float* __restrict__ qh) {
    int hk = blockIdx.x;           // 0..255
    int lane = threadIdx.x;        // 0..63
    float s = 0.f;
    for (int f = lane; f < F_; f += 64) s += q[f] * Wq[(size_t)f * HK_ + hk];
    #pragma unroll
    for (int off = 32; off; off >>= 1) s += __shfl_down(s, off);
    if (lane == 0) qh[hk] = s + bq[hk];
}

// ---------------- K2: wk[f,h] = sum_k qh[h,k]*Wk[f,h,k]; ck[h] = qh[h,:].bk[h,:] ----------------
__global__ __launch_bounds__(256) void k_wk(const float* __restrict__ qh,
                                            const float* __restrict__ Wk,
                                            const float* __restrict__ bk,
                                            float* __restrict__ wk,
                                            float* __restrict__ ck) {
    int f = blockIdx.x;            // 0..511
    int tid = threadIdx.x;         // tid = h*32+k
    __shared__ float red[256];
    red[tid] = qh[tid] * Wk[(size_t)f * HK_ + tid];
    __syncthreads();
    #pragma unroll
    for (int off = 16; off; off >>= 1) {
        if ((tid & 31) < off) red[tid] += red[tid + off];
        __syncthreads();
    }
    if ((tid & 31) == 0) wk[f * H_ + (tid >> 5)] = red[tid];
    if (f == 0 && tid < H_) {
        float c = 0.f;
        for (int k = 0; k < KD_; k++) c += qh[tid * KD_ + k] * bk[tid * KD_ + k];
        ck[tid] = c;
    }
}

// ---------------- K2b: Weff[hk,f] = sum_g Wo[hk,g]*Wd[g,f];  bWd[f] = sum_g bo[g]*Wd[g,f] ----------------
__global__ __launch_bounds__(512) void k_weff(const float* __restrict__ Wo,
                                              const float* __restrict__ Wd,
                                              const float* __restrict__ bo,
                                              float* __restrict__ weff,
                                              float* __restrict__ bwd) {
    int blk = blockIdx.x;          // 0..256 (256 = bWd row)
    int f = threadIdx.x;           // 0..511
    if (blk < HK_) {
        const float* wo = Wo + (size_t)blk * F_;   // uniform (scalar) loads
        float s = 0.f;
        for (int g = 0; g < F_; g++) s += wo[g] * Wd[(size_t)g * F_ + f];
        weff[(size_t)blk * F_ + f] = s;
    } else {
        float s = 0.f;
        for (int g = 0; g < F_; g++) s += bo[g] * Wd[(size_t)g * F_ + f];
        bwd[f] = s;
    }
}

// ---------------- K3 (fused): per (b, t-chunk): scores -> local softmax -> weighted x partial ----------------
// Writes: part[c][b][h][f] (unnormalized, chunk-local max), ml[c][b][h][{m,l}]
__global__ __launch_bounds__(256) void k_fused(const float* __restrict__ x,
                                               const float* __restrict__ wk,
                                               const float* __restrict__ ck,
                                               float* __restrict__ part,
                                               float* __restrict__ ml) {
    int c = blockIdx.x & (NC_ - 1);
    int b = blockIdx.x >> 5;
    int nt = (c < 8) ? 32 : 31;
    int t0 = (c < 8) ? c * 32 : 256 + (c - 8) * 31;
    int tid = threadIdx.x;
    int lane = tid & 63, w = tid >> 6;    // 4 waves

    __shared__ float sp[H_][33];          // scores, then p=exp(s-m)

    // --- phase 1: scores for this chunk ---
    {
        int f0 = lane * 8;
        float wreg[8][8];                 // [i][h], h contiguous in wk
        #pragma unroll
        for (int i = 0; i < 8; i++)
            #pragma unroll
            for (int h = 0; h < H_; h++) wreg[i][h] = wk[(f0 + i) * H_ + h];
        float ckv = ck[lane >> 3];
        const float scale = 0.17677669529663687f;  // 1/sqrt(32)

        for (int tl = w; tl < nt; tl += 4) {
            const float4* xr = (const float4*)(x + ((size_t)(b * T_ + t0 + tl)) * F_ + f0);
            float4 a = xr[0], bb = xr[1];
            float xv[8] = {a.x, a.y, a.z, a.w, bb.x, bb.y, bb.z, bb.w};
            float acc[8];
            #pragma unroll
            for (int h = 0; h < H_; h++) acc[h] = 0.f;
            #pragma unroll
            for (int i = 0; i < 8; i++)
                #pragma unroll
                for (int h = 0; h < H_; h++) acc[h] += xv[i] * wreg[i][h];
            // stage 1: reduce over lane bits 3..5 (all 8 accs)
            #pragma unroll
            for (int h = 0; h < H_; h++) {
                acc[h] += __shfl_xor(acc[h], 8);
                acc[h] += __shfl_xor(acc[h], 16);
                acc[h] += __shfl_xor(acc[h], 32);
            }
            // stage 2: lane picks h = lane>>3, reduce over bits 0..2
            float v = acc[0];
            #pragma unroll
            for (int h = 1; h < H_; h++) v = ((lane >> 3) == h) ? acc[h] : v;
            v += __shfl_xor(v, 1);
            v += __shfl_xor(v, 2);
            v += __shfl_xor(v, 4);
            if ((lane & 7) == 0) sp[lane >> 3][tl] = (v + ckv) * scale;
        }
    }
    __syncthreads();

    // --- local softmax stats: per h (group of 32 threads) ---
    {
        int g = tid >> 5, j = tid & 31;
        float m = -1e30f;
        if (j < nt) m = sp[g][j];
        #pragma unroll
        for (int off = 16; off; off >>= 1) m = fmaxf(m, __shfl_xor(m, off));
        float e0 = 0.f;
        if (j < nt) e0 = __expf(sp[g][j] - m);
        float l = e0;
        __syncthreads();   // everyone done reading sp as scores
        if (j < nt) sp[g][j] = e0;
        #pragma unroll
        for (int off = 16; off; off >>= 1) l += __shfl_xor(l, off);
        if (j == 0) {
            float* d = ml + ((size_t)(c * B_ + b) * H_ + g) * 2;
            d[0] = m; d[1] = l;
        }
    }
    __syncthreads();

    // --- phase 2: partial weighted sum over chunk; x re-read is L2/L3-hot ---
    {
        float acc[H_][2];
        #pragma unroll
        for (int h = 0; h < H_; h++) { acc[h][0] = 0.f; acc[h][1] = 0.f; }
        const float2* xb = (const float2*)(x + ((size_t)(b * T_ + t0)) * F_) + tid;
        for (int tt = 0; tt < nt; tt++) {
            float2 xv = xb[(size_t)tt * 256];
            #pragma unroll
            for (int h = 0; h < H_; h++) {
                float a = sp[h][tt];
                acc[h][0] += a * xv.x;
                acc[h][1] += a * xv.y;
            }
        }
        float2* dst = (float2*)(part + (size_t)(c * B_ + b) * (H_ * F_));
        #pragma unroll
        for (int h = 0; h < H_; h++)
            dst[h * (F_ / 2) + tid] = make_float2(acc[h][0], acc[h][1]);
    }
}

// ---------------- K4: pctx[c,b,hk] = sum_f part[c,b,h,f] * Wv[f,hk]  (4 chunks per block) ----------------
__global__ __launch_bounds__(256) void k_ctx(const float* __restrict__ part,
                                             const float* __restrict__ Wv,
                                             float* __restrict__ pctx) {
    int b = blockIdx.x & (B_ - 1);
    int p = blockIdx.x >> 6;       // 0..7, chunks 4p..4p+3
    int hk = threadIdx.x;
    int h = hk >> 5;
    const float* p0 = part + ((size_t)((4 * p + 0) * B_ + b) * H_ + h) * F_;
    const float* p1 = part + ((size_t)((4 * p + 1) * B_ + b) * H_ + h) * F_;
    const float* p2 = part + ((size_t)((4 * p + 2) * B_ + b) * H_ + h) * F_;
    const float* p3 = part + ((size_t)((4 * p + 3) * B_ + b) * H_ + h) * F_;
    float a0 = 0.f, a1 = 0.f, a2 = 0.f, a3 = 0.f;
    for (int f = 0; f < F_; f++) {
        float wv = Wv[(size_t)f * HK_ + hk];
        a0 += p0[f] * wv;
        a1 += p1[f] * wv;
        a2 += p2[f] * wv;
        a3 += p3[f] * wv;
    }
    pctx[((size_t)(4 * p + 0) * B_ + b) * HK_ + hk] = a0;
    pctx[((size_t)(4 * p + 1) * B_ + b) * HK_ + hk] = a1;
    pctx[((size_t)(4 * p + 2) * B_ + b) * HK_ + hk] = a2;
    pctx[((size_t)(4 * p + 3) * B_ + b) * HK_ + hk] = a3;
}

// ---------------- K5: combine chunks -> ctx -> out = ctx@Weff + bWd -> LayerNorm ----------------
__global__ __launch_bounds__(512) void k_tail(const float* __restrict__ pctx,
                                              const float* __restrict__ ml,
                                              const float* __restrict__ bv,
                                              const float* __restrict__ weff,
                                              const float* __restrict__ bwd,
                                              const float* __restrict__ gamma,
                                              const float* __restrict__ beta,
                                              float* __restrict__ out) {
    int b = blockIdx.x;
    int tid = threadIdx.x;
    __shared__ float coefs[NC_][H_];
    __shared__ float ctx_s[HK_];
    __shared__ float red[16];
    __shared__ float stat[2];

    if (tid < H_) {
        int h = tid;
        float M = -1e30f;
        #pragma unroll
        for (int c = 0; c < NC_; c++)
            M = fmaxf(M, ml[((size_t)(c * B_ + b) * H_ + h) * 2]);
        float L = 0.f;
        #pragma unroll
        for (int c = 0; c < NC_; c++) {
            const float* d = ml + ((size_t)(c * B_ + b) * H_ + h) * 2;
            L += __expf(d[0] - M) * d[1];
        }
        float invL = 1.0f / L;
        #pragma unroll
        for (int c = 0; c < NC_; c++) {
            const float* d = ml + ((size_t)(c * B_ + b) * H_ + h) * 2;
            coefs[c][h] = __expf(d[0] - M) * invL;
        }
    }
    __syncthreads();

    if (tid < HK_) {
        int h = tid >> 5;
        float s = 0.f;
        #pragma unroll
        for (int c = 0; c < NC_; c++)
            s += coefs[c][h] * pctx[((size_t)c * B_ + b) * HK_ + tid];
        ctx_s[tid] = s + bv[tid];
    }
    __syncthreads();

    // out[f] = sum_hk ctx[hk]*Weff[hk,f] + bWd[f]
    float o = bwd[tid];
    for (int hk = 0; hk < HK_; hk++) o += ctx_s[hk] * weff[(size_t)hk * F_ + tid];

    // LayerNorm over 512
    {
        float v1 = o, v2 = o * o;
        #pragma unroll
        for (int off = 32; off; off >>= 1) {
            v1 += __shfl_down(v1, off);
            v2 += __shfl_down(v2, off);
        }
        int lane = tid & 63, wid = tid >> 6;
        if (lane == 0) { red[wid] = v1; red[8 + wid] = v2; }
        __syncthreads();
        if (tid == 0) {
            float s1 = 0.f, s2 = 0.f;
            #pragma unroll
            for (int w = 0; w < 8; w++) { s1 += red[w]; s2 += red[8 + w]; }
            float mu = s1 * (1.0f / F_);
            float var = s2 * (1.0f / F_) - mu * mu;
            stat[0] = mu;
            stat[1] = rsqrtf(var + 1e-6f);
        }
        __syncthreads();
    }
    float mu = stat[0], rstd = stat[1];
    out[(size_t)b * F_ + tid] = (o - mu) * rstd * gamma[tid] + beta[tid];
}

extern "C" void kernel_launch(void* const* d_in, const int* in_sizes, int n_in,
                              void* d_out, int out_size, void* d_ws, size_t ws_size,
                              hipStream_t stream) {
    const float* x     = (const float*)d_in[0];
    const float* q     = (const float*)d_in[1];
    const float* Wq    = (const float*)d_in[2];
    const float* bq    = (const float*)d_in[3];
    const float* Wk    = (const float*)d_in[4];
    const float* bk    = (const float*)d_in[5];
    const float* Wv    = (const float*)d_in[6];
    const float* bv    = (const float*)d_in[7];
    const float* Wo    = (const float*)d_in[8];
    const float* bo    = (const float*)d_in[9];
    const float* Wd    = (const float*)d_in[10];
    const float* gamma = (const float*)d_in[11];
    const float* beta  = (const float*)d_in[12];
    float* out = (float*)d_out;

    char* ws = (char*)d_ws;
    float* qh   = (float*)(ws + 0);            // 1 KB
    float* wk   = (float*)(ws + 4096);         // 16 KB
    float* ck   = (float*)(ws + 20480);        // 32 B
    float* ml   = (float*)(ws + 24576);        // 32*64*8*2 f (128 KB)
    float* weff = (float*)(ws + 262144);       // 256*512 f (512 KB)
    float* bwd  = (float*)(ws + 786432);       // 512 f (2 KB)
    float* pctx = (float*)(ws + 1048576);      // 32*64*256 f (2 MB)
    float* part = (float*)(ws + 4194304);      // 32*64*4096 f (32 MB)

    k_qh<<<HK_, 64, 0, stream>>>(q, Wq, bq, qh);
    k_wk<<<F_, 256, 0, stream>>>(qh, Wk, bk, wk, ck);
    k_weff<<<HK_ + 1, 512, 0, stream>>>(Wo, Wd, bo, weff, bwd);
    k_fused<<<B_ * NC_, 256, 0, stream>>>(x, wk, ck, part, ml);
    k_ctx<<<(NC_ / 4) * B_, 256, 0, stream>>>(part, Wv, pctx);
    k_tail<<<B_, 512, 0, stream>>>(pctx, ml, bv, weff, bwd, gamma, beta, out);
}